// Round 1
// baseline (320.448 us; speedup 1.0000x reference)
//
#include <hip/hip_runtime.h>
#include <cstdint>
#include <cstddef>

#define VDIM 50257
#define BNUM 64
#define KNUM 8
#define TITER 20
#define TPB2 512
#define EPT ((VDIM + TPB2 - 1) / TPB2)   // 99 elements per thread in kernel 2

// ---- online max/sum-exp helpers -------------------------------------------

__device__ __forceinline__ void onl(float& m, float& s, float x) {
    if (x > m) { s = s * __expf(m - x) + 1.0f; m = x; }
    else       { s += __expf(x - m); }
}

__device__ __forceinline__ void comb(float& m, float& s, float mo, float so) {
    float mn = fmaxf(m, mo);
    s = s * __expf(m - mn) + so * __expf(mo - mn);
    m = mn;
}

template <int NWAVES>
__device__ __forceinline__ void blockReduceMS(float& m, float& s, float* shm, int tid) {
    int lane = tid & 63;
    int wid  = tid >> 6;
    #pragma unroll
    for (int off = 32; off > 0; off >>= 1) {
        float mo = __shfl_down(m, off);
        float so = __shfl_down(s, off);
        comb(m, s, mo, so);
    }
    if (lane == 0) { shm[2 * wid] = m; shm[2 * wid + 1] = s; }
    __syncthreads();
    if (tid == 0) {
        float M = shm[0], S = shm[1];
        #pragma unroll
        for (int w = 1; w < NWAVES; w++) comb(M, S, shm[2 * w], shm[2 * w + 1]);
        shm[0] = M; shm[1] = S;
    }
    __syncthreads();
    m = shm[0];
    s = shm[1];
    __syncthreads();
}

template <int NWAVES>
__device__ __forceinline__ void blockReduceArgmax(float& v, int& idx, float* shmf, int* shmi, int tid) {
    int lane = tid & 63;
    int wid  = tid >> 6;
    #pragma unroll
    for (int off = 32; off > 0; off >>= 1) {
        float vo = __shfl_down(v, off);
        int   io = __shfl_down(idx, off);
        if (vo > v || (vo == v && io < idx)) { v = vo; idx = io; }
    }
    if (lane == 0) { shmf[wid] = v; shmi[wid] = idx; }
    __syncthreads();
    if (tid == 0) {
        #pragma unroll
        for (int w = 1; w < NWAVES; w++) {
            if (shmf[w] > v || (shmf[w] == v && shmi[w] < idx)) { v = shmf[w]; idx = shmi[w]; }
        }
        shmf[0] = v; shmi[0] = idx;
    }
    __syncthreads();
    v = shmf[0];
    idx = shmi[0];
    __syncthreads();
}

// ---- kernel 1: per-row softmax stats for target & base (valid rows only) ---
// grid: 1024 blocks (0..511 target rows, 512..1023 base rows), 256 threads.

__global__ __launch_bounds__(256) void k_stats(
        const float* __restrict__ tgt, const float* __restrict__ bse,
        const int* __restrict__ draft, const int* __restrict__ ndraft,
        float* __restrict__ p_out /* [2*512]: p_llm then p_base */) {
    int id    = blockIdx.x;
    int which = id >> 9;
    int r     = id & 511;
    int k     = r & (KNUM - 1);
    int b     = r >> 3;
    if (k >= ndraft[b]) return;  // invalid draft slot: p never used

    const float* row = (which ? bse : tgt) + (size_t)r * VDIM;
    int tid = threadIdx.x;

    float m = -3.0e38f, s = 0.0f;

    // rows are only 4B-aligned (V odd): peel to 16B, then float4, then tail
    int mis  = (int)(((uintptr_t)row & 15) >> 2);
    int head = (4 - mis) & 3;
    if (tid < head) onl(m, s, row[tid]);

    const float4* v4 = (const float4*)(row + head);
    int n4 = (VDIM - head) >> 2;
    for (int g = tid; g < n4; g += 256) {
        float4 x = v4[g];
        onl(m, s, x.x); onl(m, s, x.y); onl(m, s, x.z); onl(m, s, x.w);
    }
    int done = head + (n4 << 2);
    int j = done + tid;
    if (j < VDIM) onl(m, s, row[j]);

    __shared__ float shm[16];
    blockReduceMS<4>(m, s, shm, tid);

    if (tid == 0) {
        float lse = m + __logf(s);
        int tok = draft[r];
        p_out[which * 512 + r] = __expf(row[tok] - lse);
    }
}

// ---- kernel 2: acceptance + collapsed co-steer + outputs -------------------
// grid: 64 blocks (one per request b), 512 threads.

__global__ __launch_bounds__(TPB2, 2) void k_main(
        const float* __restrict__ tgt, const float* __restrict__ bse,
        const float* __restrict__ str,
        const int* __restrict__ draft, const int* __restrict__ ndraft,
        const float* __restrict__ p_llm, const float* __restrict__ p_base,
        float* __restrict__ out_tok,   /* B*(K+1) floats */
        float* __restrict__ out_cnt,   /* B floats */
        float* __restrict__ out_fused  /* B*V floats */) {
    int b   = blockIdx.x;
    int tid = threadIdx.x;

    __shared__ int   sh_rp, sh_cnt, sh_rej;
    __shared__ float shm[16];
    __shared__ int   shmi[8];

    if (tid == 0) {
        int nd  = ndraft[b];
        int cnt = 0;
        bool chain = true;
        for (int k = 0; k < KNUM; k++) {
            float pl = p_llm[b * KNUM + k];
            float pb = p_base[b * KNUM + k];
            bool acc = (k < nd) && (pl > 0.6f * (pb + 1e-10f));
            chain = chain && acc;
            if (chain) cnt++;
        }
        int rej = (cnt < nd) ? 1 : 0;
        int rp  = cnt < (KNUM - 1) ? cnt : (KNUM - 1);
        for (int k = 0; k < KNUM; k++) {
            int tokv = (k < cnt) ? draft[b * KNUM + k] : -1;
            out_tok[b * (KNUM + 1) + k] = (float)tokv;
        }
        out_tok[b * (KNUM + 1) + KNUM] = -1.0f;  // bonus disabled
        out_cnt[b] = (float)cnt;
        sh_rp = rp; sh_cnt = cnt; sh_rej = rej;
    }
    __syncthreads();

    int rp = sh_rp;
    size_t roff = (size_t)(b * KNUM + rp) * VDIM;
    const float* tl = tgt + roff;
    const float* bl = bse + roff;
    const float* sl = str + roff;

    // Closed-form scalar recurrence: log_p_t = a_t*L + b_t*D + const(shift).
    // All log-softmax normalizations are uniform shifts and cancel; only
    // (a_T, b_T) and one final LSE are needed.
    float dd = 0.0f, ee = 0.0f, aa = 1.0f, bb = 0.0f;
    #pragma unroll
    for (int t = 1; t <= TITER; t++) {
        dd += 2.0f * (aa - 1.0f);        // ALPHA = 2
        ee += 2.0f * bb + 1.5f;          // ALPHA*b + BETA
        float tf = (float)t;
        float denom = tf * 2.0f + 0.1f;  // t*LAM + 1/ETA
        float an = (tf * 2.0f + dd + aa * 0.1f) / denom;
        float bn = (ee + bb * 0.1f) / denom;
        aa = an; bb = bn;
    }

    // Single fused pass: y = aa*tl + bb*(sl - bl); LSE + argmax of y.
    float Y[EPT];
    float m = -3.0e38f, s = 0.0f;
    float bv = -3.0e38f;
    int   bi = 0x7fffffff;
    #pragma unroll
    for (int i = 0; i < EPT; i++) {
        int j = tid + i * TPB2;
        float y = 0.0f;
        if (j < VDIM) {
            y = aa * tl[j] + bb * (sl[j] - bl[j]);
            onl(m, s, y);
            if (y > bv) { bv = y; bi = j; }
        }
        Y[i] = y;
    }
    blockReduceMS<8>(m, s, shm, tid);
    float Z = m + __logf(s);
    blockReduceArgmax<8>(bv, bi, shm, shmi, tid);

    #pragma unroll
    for (int i = 0; i < EPT; i++) {
        int j = tid + i * TPB2;
        if (j < VDIM) out_fused[(size_t)b * VDIM + j] = Y[i] - Z;
    }

    if (tid == 0 && sh_rej) {
        out_tok[b * (KNUM + 1) + sh_cnt] = (float)bi;  // recovered token
    }
}

// ---- host launcher ---------------------------------------------------------

extern "C" void kernel_launch(void* const* d_in, const int* in_sizes, int n_in,
                              void* d_out, int out_size, void* d_ws, size_t ws_size,
                              hipStream_t stream) {
    const float* tgt   = (const float*)d_in[0];
    const float* bse   = (const float*)d_in[1];
    const float* str   = (const float*)d_in[2];
    const int*   draft = (const int*)d_in[3];
    const int*   nd    = (const int*)d_in[4];
    // d_in[5] (bonus_token_ids) unused: ENABLE_BONUS == False

    float* out       = (float*)d_out;
    float* out_tok   = out;                             // 64*9
    float* out_cnt   = out + BNUM * (KNUM + 1);         // 64
    float* out_fused = out + BNUM * (KNUM + 1) + BNUM;  // 64*50257

    float* p_llm  = (float*)d_ws;            // 512 floats
    float* p_base = p_llm + BNUM * KNUM;     // 512 floats

    hipLaunchKernelGGL(k_stats, dim3(1024), dim3(256), 0, stream,
                       tgt, bse, draft, nd, p_llm);
    hipLaunchKernelGGL(k_main, dim3(BNUM), dim3(TPB2), 0, stream,
                       tgt, bse, str, draft, nd, p_llm, p_llm + BNUM * KNUM,
                       out_tok, out_cnt, out_fused);
}